// Round 1
// baseline (44.266 us; speedup 1.0000x reference)
//
#include <hip/hip_runtime.h>

#define EPS_A 1e-12f
#define BIG   1e30f

__device__ __forceinline__ void compute_ray(float px, float py, float vx, float vy, float A,
                                            float& cpx, float& cpy, float& ox, float& oy) {
    float a = A * vy * vy;
    float b = 2.0f * A * py * vy - vx;
    float c = A * py * py - px;
    float disc = b * b - 4.0f * a * c;
    float sq = sqrtf(fmaxf(disc, 0.0f));
    float sgn_b = (b >= 0.0f) ? 1.0f : -1.0f;
    float q = -0.5f * (b + sgn_b * sq);
    float a_safe = (fabsf(a) < EPS_A) ? 1.0f : a;
    float q_safe = (fabsf(q) < EPS_A) ? 1.0f : q;
    float r1 = c / q_safe;
    float r2 = q / a_safe;
    float r1p = (r1 > 0.0f) ? r1 : BIG;
    float r2p = (r2 > 0.0f) ? r2 : BIG;
    float t_quad = fminf(r1p, r2p);
    float b_safe = (fabsf(b) < EPS_A) ? 1.0f : b;
    float t_lin = -c / b_safe;
    float t = (fabsf(a) < EPS_A) ? t_lin : t_quad;

    cpx = px + t * vx;
    cpy = py + t * vy;

    float ny = -2.0f * A * cpy;
    float inv_norm = 1.0f / sqrtf(1.0f + ny * ny);
    float nx = inv_norm;
    float nyn = ny * inv_norm;
    float dot = nx * vx + nyn * vy;
    if (dot > 0.0f) { nx = -nx; nyn = -nyn; }

    const float eta = (float)(1.0 / 1.5);
    float cosi = -(nx * vx + nyn * vy);
    float k = 1.0f - eta * eta * (1.0f - cosi * cosi);
    float cost = sqrtf(fmaxf(k, 0.0f));
    float coef = eta * cosi - cost;
    float rfx = eta * vx + coef * nx;
    float rfy = eta * vy + coef * nyn;
    float tc = 2.0f * cosi;
    float rlx = vx + tc * nx;
    float rly = vy + tc * nyn;
    bool refl = (k < 0.0f);
    ox = refl ? rlx : rfx;
    oy = refl ? rly : rfy;
}

__global__ void __launch_bounds__(256)
RefractiveSurface_kernel(const float4* __restrict__ orig,
                         const float4* __restrict__ vec,
                         const float* __restrict__ Aptr,
                         float4* __restrict__ out_cp,
                         float4* __restrict__ out_v,
                         int npairs, int ntail_ray /* index of odd tail ray or -1 */,
                         const float2* __restrict__ orig2,
                         const float2* __restrict__ vec2,
                         float2* __restrict__ out_cp2,
                         float2* __restrict__ out_v2) {
    const float A = Aptr[0];
    int stride = gridDim.x * blockDim.x;
    for (int i = blockIdx.x * blockDim.x + threadIdx.x; i < npairs; i += stride) {
        float4 o = orig[i];
        float4 v = vec[i];
        float4 cp, ov;
        compute_ray(o.x, o.y, v.x, v.y, A, cp.x, cp.y, ov.x, ov.y);
        compute_ray(o.z, o.w, v.z, v.w, A, cp.z, cp.w, ov.z, ov.w);
        out_cp[i] = cp;
        out_v[i] = ov;
    }
    // odd-N tail (not hit for N=8M, kept for generality)
    if (ntail_ray >= 0 && blockIdx.x == 0 && threadIdx.x == 0) {
        float2 o = orig2[ntail_ray];
        float2 v = vec2[ntail_ray];
        float2 cp, ov;
        compute_ray(o.x, o.y, v.x, v.y, A, cp.x, cp.y, ov.x, ov.y);
        out_cp2[ntail_ray] = cp;
        out_v2[ntail_ray] = ov;
    }
}

extern "C" void kernel_launch(void* const* d_in, const int* in_sizes, int n_in,
                              void* d_out, int out_size, void* d_ws, size_t ws_size,
                              hipStream_t stream) {
    const float* origins = (const float*)d_in[0];
    const float* vectors = (const float*)d_in[1];
    const float* Aptr    = (const float*)d_in[2];

    const int N = in_sizes[0] / 2;         // number of rays
    const int npairs = N / 2;              // 2 rays per thread via float4
    const int ntail = (N & 1) ? (N - 1) : -1;

    float* out = (float*)d_out;
    float* out_cp = out;                   // collision_points: first 2N floats
    float* out_v  = out + (size_t)2 * N;   // out_vectors: next 2N floats

    const int block = 256;
    int grid = (npairs + block - 1) / block;
    if (grid > 4096) grid = 4096;
    if (grid < 1) grid = 1;

    RefractiveSurface_kernel<<<grid, block, 0, stream>>>(
        (const float4*)origins, (const float4*)vectors, Aptr,
        (float4*)out_cp, (float4*)out_v,
        npairs, ntail,
        (const float2*)origins, (const float2*)vectors,
        (float2*)out_cp, (float2*)out_v);
}